// Round 4
// baseline (419.197 us; speedup 1.0000x reference)
//
#include <hip/hip_runtime.h>
#include <hip/hip_bf16.h>
#include <math.h>

#define BATCH 32
#define C 256
#define HW 3136
#define OUTROW 32896
#define KSPLIT 7
#define KCHUNK 448   // HW / KSPLIT
#define KC32 98      // HW / 32
#define KCG 49       // kc-pair groups per batch
#define SLAB 16384   // shorts per kc slab (hi 8192 + lo 8192 interleaved)
#define HALF 8192

// Interleaved fragment-major layouts (shorts):
//   X slab s = b*98 + kc :  X[s*SLAB + row*32 + (k&31)]        (hi)
//                           X[s*SLAB + HALF + row*32 + (k&31)] (lo)
//   M slab s = b*8 + kc  :  same, 256x256 matrices, 8 slabs each.

typedef __bf16 b8v __attribute__((ext_vector_type(8)));
typedef float  f4v __attribute__((ext_vector_type(4)));
typedef unsigned short u16x8 __attribute__((ext_vector_type(8)));

__device__ __forceinline__ unsigned short f2bf(float f) {
    union { float f; unsigned u; } v; v.f = f;
    unsigned r = v.u + 0x7FFFu + ((v.u >> 16) & 1u);
    return (unsigned short)(r >> 16);
}
__device__ __forceinline__ float bf2f(unsigned short h) {
    union { unsigned u; float f; } v; v.u = ((unsigned)h) << 16; return v.f;
}
__device__ __forceinline__ void split2(float x, unsigned short& h, unsigned short& l) {
    h = f2bf(x);
    l = f2bf(x - bf2f(h));
}

__device__ __forceinline__ float wave_sum(float v) {
    for (int o = 32; o; o >>= 1) v += __shfl_down(v, o, 64);
    return v;
}

// ---------------------------------------------------------------------------
// prep: x -> hi/lo bf16 split, interleaved fragment-major X layout.
// ---------------------------------------------------------------------------
__global__ __launch_bounds__(256) void k_prep(const float* __restrict__ x,
                                              unsigned short* __restrict__ X,
                                              float* __restrict__ psum,
                                              float* __restrict__ qsum) {
    const int blk = blockIdx.x;                 // b*KCG + g
    const int b = blk / KCG;
    const int g = blk - b * KCG;
    const int kc0 = g * 2;
    const int t = threadIdx.x;
    const int lane4 = t & 3;                    // 4 lanes per row, 16 floats each
    const int rowoff = t >> 2;                  // 0..63
    const int ko = lane4 * 8;

    const float* xb = x + (size_t)b * C * HW + (size_t)kc0 * 32 + ko;
    unsigned short* s0 = X + (size_t)(b * KC32 + kc0) * SLAB + ko;
    unsigned short* s1 = s0 + SLAB;
    float* ps = psum + (size_t)blk * 256;
    float* qs = qsum + (size_t)blk * 256;

#pragma unroll
    for (int it = 0; it < 4; ++it) {
        const int row = it * 64 + rowoff;
        const float* src = xb + (size_t)row * HW;
        float4 v0 = *(const float4*)(src);
        float4 v1 = *(const float4*)(src + 4);
        float4 v2 = *(const float4*)(src + 32);
        float4 v3 = *(const float4*)(src + 36);
        float va[8] = { v0.x, v0.y, v0.z, v0.w, v1.x, v1.y, v1.z, v1.w };
        float vb[8] = { v2.x, v2.y, v2.z, v2.w, v3.x, v3.y, v3.z, v3.w };
        unsigned short ha[8], la[8], hb[8], lb[8];
        float s = 0.f, q = 0.f;
#pragma unroll
        for (int j = 0; j < 8; ++j) {
            split2(va[j], ha[j], la[j]);
            split2(vb[j], hb[j], lb[j]);
            s += va[j] + vb[j];
            q = fmaf(va[j], va[j], q);
            q = fmaf(vb[j], vb[j], q);
        }
        *(u16x8*)(s0 + row * 32) = *(u16x8*)ha;
        *(u16x8*)(s0 + HALF + row * 32) = *(u16x8*)la;
        *(u16x8*)(s1 + row * 32) = *(u16x8*)hb;
        *(u16x8*)(s1 + HALF + row * 32) = *(u16x8*)lb;
        s += __shfl_xor(s, 1, 64);
        s += __shfl_xor(s, 2, 64);
        q += __shfl_xor(q, 1, 64);
        q += __shfl_xor(q, 2, 64);
        if (lane4 == 0) { ps[row] = s; qs[row] = q; }
    }
}

// reduce per-kcg partials -> sbuf (row sums) + trace
__global__ __launch_bounds__(256) void k_tr(const float* __restrict__ psum,
                                            const float* __restrict__ qsum,
                                            float* __restrict__ sbuf,
                                            float* __restrict__ trbuf,
                                            float* __restrict__ strbuf) {
    const int b = blockIdx.x, t = threadIdx.x;
    const float* ps = psum + (size_t)b * KCG * 256 + t;
    const float* qs = qsum + (size_t)b * KCG * 256 + t;
    float s = 0.f, q = 0.f;
#pragma unroll 7
    for (int g = 0; g < KCG; ++g) {
        s += ps[(size_t)g * 256];
        q += qs[(size_t)g * 256];
    }
    sbuf[b * C + t] = s;
    const float invn = 1.f / (float)HW, invn2 = invn * invn;
    float v = q * invn - s * s * invn2;
    v = wave_sum(v);
    __shared__ float red[4];
    if ((t & 63) == 0) red[t >> 6] = v;
    __syncthreads();
    if (t == 0) {
        float tr = red[0] + red[1] + red[2] + red[3];
        trbuf[b] = tr;
        strbuf[b] = sqrtf(tr);
    }
}

// ---------------------------------------------------------------------------
// gram split-K: 1-wave blocks, 64x64 tile, fragment-major coalesced loads,
// register dbuf, XCD-pinned. Grid 2240 x 64.
// ---------------------------------------------------------------------------
__global__ __launch_bounds__(64) void k_gram_split(
    const unsigned short* __restrict__ X, float* __restrict__ part) {
    const int bid = blockIdx.x;
    const int x8 = bid & 7;
    const int t8 = bid >> 3;
    const int pairIdx = t8 % 10;
    const int g = (t8 / 10) * 8 + x8;   // 0..223, pinned to XCD x8
    const int b = g & 31;
    const int z = g >> 5;               // 0..6

    int p = pairIdx, tm = 0, rem = 4;
    while (p >= rem) { p -= rem; ++tm; --rem; }
    const int tn = tm + p;

    const int lane = threadIdx.x & 63;
    const int q = lane >> 4, r = lane & 15;
    const int kc0 = z * (KCHUNK / 32);
    const size_t matb = (size_t)b * KC32 * SLAB;

    int oA[4], oB[4];
#pragma unroll
    for (int i = 0; i < 4; ++i) {
        oA[i] = (tm * 64 + i * 16 + r) * 32 + q * 8;
        oB[i] = (tn * 64 + i * 16 + r) * 32 + q * 8;
    }

    f4v acc[4][4] = {};
    b8v fAh[2][4], fAl[2][4], fBh[2][4], fBl[2][4];
#define LDG(buf, kc)                                                     \
    do {                                                                 \
        const size_t sb = matb + (size_t)(kc0 + (kc)) * SLAB;            \
        for (int i = 0; i < 4; ++i) {                                    \
            fAh[buf][i] = *(const b8v*)(X + sb + oA[i]);                 \
            fAl[buf][i] = *(const b8v*)(X + sb + HALF + oA[i]);          \
            fBh[buf][i] = *(const b8v*)(X + sb + oB[i]);                 \
            fBl[buf][i] = *(const b8v*)(X + sb + HALF + oB[i]);          \
        }                                                                \
    } while (0)

    LDG(0, 0);
#pragma unroll
    for (int kc = 0; kc < KCHUNK / 32; ++kc) {
        const int cb = kc & 1, nb = cb ^ 1;
        if (kc < KCHUNK / 32 - 1) LDG(nb, kc + 1);
#pragma unroll
        for (int i = 0; i < 4; ++i)
#pragma unroll
            for (int j = 0; j < 4; ++j) {
                acc[i][j] = __builtin_amdgcn_mfma_f32_16x16x32_bf16(fAh[cb][i], fBh[cb][j], acc[i][j], 0, 0, 0);
                acc[i][j] = __builtin_amdgcn_mfma_f32_16x16x32_bf16(fAh[cb][i], fBl[cb][j], acc[i][j], 0, 0, 0);
                acc[i][j] = __builtin_amdgcn_mfma_f32_16x16x32_bf16(fAl[cb][i], fBh[cb][j], acc[i][j], 0, 0, 0);
            }
    }
#undef LDG

    float* pt = part + (((size_t)pairIdx * BATCH + b) * KSPLIT + z) * 4096;
#pragma unroll
    for (int i = 0; i < 4; ++i)
#pragma unroll
        for (int j = 0; j < 4; ++j)
#pragma unroll
            for (int reg = 0; reg < 4; ++reg) {
                int row = i * 16 + q * 4 + reg;
                int col = j * 16 + r;
                pt[row * 64 + col] = acc[i][j][reg];
            }
}

// ---------------------------------------------------------------------------
// reduce partials -> a and z0 (interleaved fragment-major), mirrored via LDS
// ---------------------------------------------------------------------------
__global__ __launch_bounds__(256) void k_reduce(
    const float* __restrict__ part, const float* __restrict__ sbuf,
    const float* __restrict__ trbuf,
    unsigned short* __restrict__ A, unsigned short* __restrict__ Z) {
    const int b = blockIdx.y;
    int p = blockIdx.x, tm = 0, rem = 4;
    while (p >= rem) { p -= rem; ++tm; --rem; }
    const int tn = tm + p;

    const float* pb = part + ((size_t)blockIdx.x * BATCH + b) * KSPLIT * 4096;
    const int t = threadIdx.x;
    const int row = t >> 2, c0 = (t & 3) * 16;

    float s[16];
#pragma unroll
    for (int u = 0; u < 16; ++u) s[u] = 0.f;
    for (int sp = 0; sp < KSPLIT; ++sp) {
        const float* q4 = pb + sp * 4096 + row * 64 + c0;
#pragma unroll
        for (int u4 = 0; u4 < 4; ++u4) {
            float4 v = *(const float4*)(q4 + u4 * 4);
            s[u4 * 4 + 0] += v.x; s[u4 * 4 + 1] += v.y;
            s[u4 * 4 + 2] += v.z; s[u4 * 4 + 3] += v.w;
        }
    }

    const float invn = 1.f / (float)HW, invn2 = invn * invn;
    const float tr = trbuf[b];
    const int gi = tm * 64 + row;
    const float si = sbuf[b * C + gi];
    const size_t mb = (size_t)b * 8 * SLAB;

    __shared__ unsigned short tAh[64][66], tAl[64][66], tZh[64][66], tZl[64][66];
    unsigned short vAh[16], vAl[16], vZh[16], vZl[16];
#pragma unroll
    for (int u = 0; u < 16; ++u) {
        int gj = tn * 64 + c0 + u;
        float sj = sbuf[b * C + gj];
        float a = (s[u] * invn - si * sj * invn2) / tr;
        split2(a, vAh[u], vAl[u]);
        float zv = ((gi == gj) ? 1.5f : 0.f) - 0.5f * a;
        split2(zv, vZh[u], vZl[u]);
        tAh[row][c0 + u] = vAh[u]; tAl[row][c0 + u] = vAl[u];
        tZh[row][c0 + u] = vZh[u]; tZl[row][c0 + u] = vZl[u];
    }
#pragma unroll
    for (int u4 = 0; u4 < 4; ++u4) {
        const int col0 = tn * 64 + c0 + u4 * 4;
        const size_t off = mb + (size_t)(col0 >> 5) * SLAB + (size_t)gi * 32 + (col0 & 31);
        *(ushort4*)&A[off] = *(ushort4*)&vAh[u4 * 4];
        *(ushort4*)&A[off + HALF] = *(ushort4*)&vAl[u4 * 4];
        *(ushort4*)&Z[off] = *(ushort4*)&vZh[u4 * 4];
        *(ushort4*)&Z[off + HALF] = *(ushort4*)&vZl[u4 * 4];
    }
    if (tm != tn) {
        __syncthreads();
        const int mr = t >> 2, mc0 = (t & 3) * 16;
        const int gim = tn * 64 + mr;
        unsigned short wAh[16], wAl[16], wZh[16], wZl[16];
#pragma unroll
        for (int u = 0; u < 16; ++u) {
            wAh[u] = tAh[mc0 + u][mr]; wAl[u] = tAl[mc0 + u][mr];
            wZh[u] = tZh[mc0 + u][mr]; wZl[u] = tZl[mc0 + u][mr];
        }
#pragma unroll
        for (int u4 = 0; u4 < 4; ++u4) {
            const int col0 = tm * 64 + mc0 + u4 * 4;
            const size_t off = mb + (size_t)(col0 >> 5) * SLAB + (size_t)gim * 32 + (col0 & 31);
            *(ushort4*)&A[off] = *(ushort4*)&wAh[u4 * 4];
            *(ushort4*)&A[off + HALF] = *(ushort4*)&wAl[u4 * 4];
            *(ushort4*)&Z[off] = *(ushort4*)&wZh[u4 * 4];
            *(ushort4*)&Z[off + HALF] = *(ushort4*)&wZl[u4 * 4];
        }
    }
}

// ---------------------------------------------------------------------------
// NS core, 2-wave split-K: each wave computes the full 64x64 tile over half
// of K (4 kc), then an LDS exchange swaps row-halves: wave0 keeps rows 0-31,
// wave1 rows 32-63. Halves the serial load-stall chain, doubles waves/SIMD.
// ---------------------------------------------------------------------------
__device__ __forceinline__ void wave_gemm64h(
    const unsigned short* __restrict__ A, const unsigned short* __restrict__ B,
    int rowA, int rowB, int kcBase, f4v acc[4][4]) {
    const int lane = threadIdx.x & 63;
    const int q = lane >> 4, r = lane & 15;
    int oA[4], oB[4];
#pragma unroll
    for (int i = 0; i < 4; ++i) {
        oA[i] = (rowA + i * 16 + r) * 32 + q * 8;
        oB[i] = (rowB + i * 16 + r) * 32 + q * 8;
    }
    b8v fAh[2][4], fAl[2][4], fBh[2][4], fBl[2][4];
#define LD(buf, kc)                                              \
    do {                                                         \
        const size_t sb = (size_t)(kcBase + (kc)) * SLAB;        \
        for (int i = 0; i < 4; ++i) {                            \
            fAh[buf][i] = *(const b8v*)(A + sb + oA[i]);         \
            fAl[buf][i] = *(const b8v*)(A + sb + HALF + oA[i]);  \
            fBh[buf][i] = *(const b8v*)(B + sb + oB[i]);         \
            fBl[buf][i] = *(const b8v*)(B + sb + HALF + oB[i]);  \
        }                                                        \
    } while (0)

    LD(0, 0);
#pragma unroll
    for (int kc = 0; kc < 4; ++kc) {
        const int cb = kc & 1, nb = cb ^ 1;
        if (kc < 3) LD(nb, kc + 1);
#pragma unroll
        for (int i = 0; i < 4; ++i)
#pragma unroll
            for (int j = 0; j < 4; ++j) {
                acc[i][j] = __builtin_amdgcn_mfma_f32_16x16x32_bf16(fAh[cb][i], fBh[cb][j], acc[i][j], 0, 0, 0);
                acc[i][j] = __builtin_amdgcn_mfma_f32_16x16x32_bf16(fAh[cb][i], fBl[cb][j], acc[i][j], 0, 0, 0);
                acc[i][j] = __builtin_amdgcn_mfma_f32_16x16x32_bf16(fAl[cb][i], fBh[cb][j], acc[i][j], 0, 0, 0);
            }
    }
#undef LD
}

// LDS exchange: wave wv gives rows it doesn't keep, receives the other
// wave's contribution to its kept rows. keep = wv*2 (first kept i).
__device__ __forceinline__ void exchange_halves(f4v acc[4][4],
                                                f4v (*xbuf)[2][4][64], int wv) {
    const int lane = threadIdx.x & 63;
    const int keep = wv * 2, give = 2 - keep;
#pragma unroll
    for (int i2 = 0; i2 < 2; ++i2)
#pragma unroll
        for (int j = 0; j < 4; ++j)
            xbuf[wv][i2][j][lane] = acc[give + i2][j];
    __syncthreads();
#pragma unroll
    for (int i2 = 0; i2 < 2; ++i2)
#pragma unroll
        for (int j = 0; j < 4; ++j)
            acc[keep + i2][j] += xbuf[wv ^ 1][i2][j][lane];
}

// store this wave's 32-row half into interleaved fragment-major D (direct)
__device__ __forceinline__ void store_half_fm(
    unsigned short* __restrict__ D, int tm, int tn,
    const f4v acc[4][4], int keep, bool modeT) {
    const int lane = threadIdx.x & 63, q = lane >> 4, r = lane & 15;
#pragma unroll
    for (int i2 = 0; i2 < 2; ++i2)
#pragma unroll
        for (int j = 0; j < 4; ++j) {
            const int gj = tn * 64 + j * 16 + r;
            const size_t cbase = (size_t)(gj >> 5) * SLAB + (gj & 31);
#pragma unroll
            for (int reg = 0; reg < 4; ++reg) {
                const int gi = tm * 64 + (keep + i2) * 16 + q * 4 + reg;
                float v = acc[keep + i2][j][reg];
                if (modeT) v = ((gi == gj) ? 1.5f : 0.f) - 0.5f * v;
                unsigned short h, l;
                split2(v, h, l);
                D[cbase + (size_t)gi * 32] = h;
                D[cbase + HALF + (size_t)gi * 32] = l;
            }
        }
}

// MODE 0: D = acc ; MODE 1: D = 1.5I - 0.5 acc ; MODE 2: triuvec(acc*sqrt(tr))
// XCD-pinned flat grid: batch b always lands on XCD b%8. 128 threads/block.
template <int MODE>
__global__ __launch_bounds__(128) void k_t64(
    const unsigned short* __restrict__ A, const unsigned short* __restrict__ B,
    unsigned short* __restrict__ D, float* __restrict__ outF,
    const float* __restrict__ strbuf) {
    const int bid = blockIdx.x;
    const int x8 = bid & 7;
    const int w = bid >> 3;
    int b, tm = 0, tn = 0;
    if (MODE == 2) {
        b = x8 + 8 * (w / 10);
        int p = w % 10, rem = 4;
        while (p >= rem) { p -= rem; ++tm; --rem; }
        tn = tm + p;
    } else {
        b = x8 + 8 * (w >> 4);
        const int tile = w & 15;
        tm = tile >> 2; tn = tile & 3;
    }
    const int wv = threadIdx.x >> 6;
    const size_t mo = (size_t)b * 8 * SLAB;
    f4v acc[4][4] = {};
    wave_gemm64h(A + mo, B + mo, tm * 64, tn * 64, wv * 4, acc);

    __shared__ f4v xbuf[2][2][4][64];
    exchange_halves(acc, xbuf, wv);
    const int keep = wv * 2;

    if (MODE == 2) {
        const int lane = threadIdx.x & 63, q = lane >> 4, r = lane & 15;
        const float sc = strbuf[b];
#pragma unroll
        for (int i2 = 0; i2 < 2; ++i2)
#pragma unroll
            for (int j = 0; j < 4; ++j) {
                const int gj = tn * 64 + j * 16 + r;
#pragma unroll
                for (int reg = 0; reg < 4; ++reg) {
                    const int gi = tm * 64 + (keep + i2) * 16 + q * 4 + reg;
                    if (gj >= gi)
                        outF[(size_t)b * OUTROW + (size_t)(gi * C - (gi * (gi - 1)) / 2) +
                             (gj - gi)] = acc[keep + i2][j][reg] * sc;
                }
            }
    } else {
        store_half_fm(D + mo, tm, tn, acc, keep, MODE == 1);
    }
}

// fused Ynew = Y@T, Znew = T@Z ; XCD-pinned flat grid (1024 blocks x 128)
__global__ __launch_bounds__(128) void k_yz64(
    const unsigned short* __restrict__ Y, const unsigned short* __restrict__ T,
    const unsigned short* __restrict__ Z,
    unsigned short* __restrict__ Yn, unsigned short* __restrict__ Zn) {
    const int bid = blockIdx.x;
    const int x8 = bid & 7;
    const int w = bid >> 3;                 // 0..127
    const int b = x8 + 8 * ((w >> 4) & 3);
    const int zz = w >> 6;                  // 0: Y@T, 1: T@Z
    const int tile = w & 15;
    const int tm = tile >> 2, tn = tile & 3;

    const unsigned short* Am = zz ? T : Y;
    const unsigned short* Bm = zz ? Z : T;
    unsigned short* Dm = zz ? Zn : Yn;

    const int wv = threadIdx.x >> 6;
    const size_t mo = (size_t)b * 8 * SLAB;
    f4v acc[4][4] = {};
    wave_gemm64h(Am + mo, Bm + mo, tm * 64, tn * 64, wv * 4, acc);

    __shared__ f4v xbuf[2][2][4][64];
    exchange_halves(acc, xbuf, wv);
    store_half_fm(Dm + mo, tm, tn, acc, wv * 2, false);
}

// ---------------------------------------------------------------------------
extern "C" void kernel_launch(void* const* d_in, const int* in_sizes, int n_in,
                              void* d_out, int out_size, void* d_ws, size_t ws_size,
                              hipStream_t stream) {
    const float* x = (const float*)d_in[0];
    float* out = (float*)d_out;

    unsigned short* W = (unsigned short*)d_ws;
    const size_t XS = (size_t)BATCH * KC32 * SLAB;   // interleaved X shorts
    const size_t MS = (size_t)BATCH * 8 * SLAB;      // one interleaved matrix set
    unsigned short* X = W;
    float* sbuf = (float*)(X + XS);
    float* trbuf = sbuf + BATCH * C;
    float* strbuf = trbuf + BATCH;
    unsigned short* P = (unsigned short*)(strbuf + BATCH);
    unsigned short* PA = P + 0 * MS;
    unsigned short* PB = P + 1 * MS;
    unsigned short* PC = P + 2 * MS;
    unsigned short* PD = P + 3 * MS;
    unsigned short* PE = P + 4 * MS;
    // fp32 gram partials alias PC.. (dead until Y0 is written)
    float* part = (float*)PC;                         // 10*32*7*4096 floats
    // prep sum partials alias PA (dead until k_reduce writes it)
    float* psum = (float*)PA;                         // 32*49*256 floats
    float* qsum = psum + (size_t)BATCH * KCG * 256;

    k_prep<<<dim3(BATCH * KCG), 256, 0, stream>>>(x, X, psum, qsum);
    k_tr<<<dim3(BATCH), 256, 0, stream>>>(psum, qsum, sbuf, trbuf, strbuf);
    k_gram_split<<<dim3(10 * BATCH * KSPLIT), 64, 0, stream>>>(X, part);
    k_reduce<<<dim3(10, BATCH), 256, 0, stream>>>(part, sbuf, trbuf, PA, PB);

    dim3 g512(512);
    // Y0 = a @ z0 -> PC
    k_t64<0><<<g512, 128, 0, stream>>>(PA, PB, PC, nullptr, strbuf);
    // it0: T0 = 1.5I - 0.5 Z0@Y0 = PB@PC -> PD ; Y1 = PC@PD -> PA ; Z1 = PD@PB -> PE
    k_t64<1><<<g512, 128, 0, stream>>>(PB, PC, PD, nullptr, strbuf);
    k_yz64<<<dim3(1024), 128, 0, stream>>>(PC, PD, PB, PA, PE);
    // it1: T1 = PE@PA -> PB ; Y2 = PA@PB -> PC ; Z2 = PB@PE -> PD
    k_t64<1><<<g512, 128, 0, stream>>>(PE, PA, PB, nullptr, strbuf);
    k_yz64<<<dim3(1024), 128, 0, stream>>>(PA, PB, PE, PC, PD);
    // it2: T2 = PD@PC -> PA ; Y3 = PC@PA -> PB ; Z3 = PA@PD -> PE
    k_t64<1><<<g512, 128, 0, stream>>>(PD, PC, PA, nullptr, strbuf);
    k_yz64<<<dim3(1024), 128, 0, stream>>>(PC, PA, PD, PB, PE);
    // it3: T3 = PE@PB -> PC ; out = triuvec((PB@PC) * sqrt(tr))
    k_t64<1><<<g512, 128, 0, stream>>>(PE, PB, PC, nullptr, strbuf);
    k_t64<2><<<dim3(320), 128, 0, stream>>>(PB, PC, nullptr, out, strbuf);
}

// Round 6
// 364.475 us; speedup vs baseline: 1.1501x; 1.1501x over previous
//
#include <hip/hip_runtime.h>
#include <hip/hip_bf16.h>
#include <math.h>

#define BATCH 32
#define C 256
#define HW 3136
#define OUTROW 32896
#define KSPLIT 7
#define KCHUNK 448   // HW / KSPLIT
#define KC32 98      // HW / 32
#define KCG 49       // kc-pair groups per batch
#define SLAB 16384   // shorts per kc slab (hi 8192 + lo 8192 interleaved)
#define HALF 8192

// Interleaved fragment-major layouts (shorts):
//   X slab s = b*98 + kc :  X[s*SLAB + row*32 + (k&31)]        (hi)
//                           X[s*SLAB + HALF + row*32 + (k&31)] (lo)
//   M slab s = b*8 + kc  :  same, 256x256 matrices, 8 slabs each.

typedef __bf16 b8v __attribute__((ext_vector_type(8)));
typedef float  f4v __attribute__((ext_vector_type(4)));
typedef unsigned short u16x8 __attribute__((ext_vector_type(8)));

__device__ __forceinline__ unsigned short f2bf(float f) {
    union { float f; unsigned u; } v; v.f = f;
    unsigned r = v.u + 0x7FFFu + ((v.u >> 16) & 1u);
    return (unsigned short)(r >> 16);
}
__device__ __forceinline__ float bf2f(unsigned short h) {
    union { unsigned u; float f; } v; v.u = ((unsigned)h) << 16; return v.f;
}
__device__ __forceinline__ void split2(float x, unsigned short& h, unsigned short& l) {
    h = f2bf(x);
    l = f2bf(x - bf2f(h));
}

__device__ __forceinline__ float wave_sum(float v) {
    for (int o = 32; o; o >>= 1) v += __shfl_down(v, o, 64);
    return v;
}

// ---------------------------------------------------------------------------
// prep: x -> hi/lo bf16 split, interleaved fragment-major X layout.
// ---------------------------------------------------------------------------
__global__ __launch_bounds__(256) void k_prep(const float* __restrict__ x,
                                              unsigned short* __restrict__ X,
                                              float* __restrict__ psum,
                                              float* __restrict__ qsum) {
    const int blk = blockIdx.x;                 // b*KCG + g
    const int b = blk / KCG;
    const int g = blk - b * KCG;
    const int kc0 = g * 2;
    const int t = threadIdx.x;
    const int lane4 = t & 3;                    // 4 lanes per row, 16 floats each
    const int rowoff = t >> 2;                  // 0..63
    const int ko = lane4 * 8;

    const float* xb = x + (size_t)b * C * HW + (size_t)kc0 * 32 + ko;
    unsigned short* s0 = X + (size_t)(b * KC32 + kc0) * SLAB + ko;
    unsigned short* s1 = s0 + SLAB;
    float* ps = psum + (size_t)blk * 256;
    float* qs = qsum + (size_t)blk * 256;

#pragma unroll
    for (int it = 0; it < 4; ++it) {
        const int row = it * 64 + rowoff;
        const float* src = xb + (size_t)row * HW;
        float4 v0 = *(const float4*)(src);
        float4 v1 = *(const float4*)(src + 4);
        float4 v2 = *(const float4*)(src + 32);
        float4 v3 = *(const float4*)(src + 36);
        float va[8] = { v0.x, v0.y, v0.z, v0.w, v1.x, v1.y, v1.z, v1.w };
        float vb[8] = { v2.x, v2.y, v2.z, v2.w, v3.x, v3.y, v3.z, v3.w };
        unsigned short ha[8], la[8], hb[8], lb[8];
        float s = 0.f, q = 0.f;
#pragma unroll
        for (int j = 0; j < 8; ++j) {
            split2(va[j], ha[j], la[j]);
            split2(vb[j], hb[j], lb[j]);
            s += va[j] + vb[j];
            q = fmaf(va[j], va[j], q);
            q = fmaf(vb[j], vb[j], q);
        }
        *(u16x8*)(s0 + row * 32) = *(u16x8*)ha;
        *(u16x8*)(s0 + HALF + row * 32) = *(u16x8*)la;
        *(u16x8*)(s1 + row * 32) = *(u16x8*)hb;
        *(u16x8*)(s1 + HALF + row * 32) = *(u16x8*)lb;
        s += __shfl_xor(s, 1, 64);
        s += __shfl_xor(s, 2, 64);
        q += __shfl_xor(q, 1, 64);
        q += __shfl_xor(q, 2, 64);
        if (lane4 == 0) { ps[row] = s; qs[row] = q; }
    }
}

// reduce per-kcg partials -> sbuf (row sums) + trace
__global__ __launch_bounds__(256) void k_tr(const float* __restrict__ psum,
                                            const float* __restrict__ qsum,
                                            float* __restrict__ sbuf,
                                            float* __restrict__ trbuf,
                                            float* __restrict__ strbuf) {
    const int b = blockIdx.x, t = threadIdx.x;
    const float* ps = psum + (size_t)b * KCG * 256 + t;
    const float* qs = qsum + (size_t)b * KCG * 256 + t;
    float s = 0.f, q = 0.f;
#pragma unroll 7
    for (int g = 0; g < KCG; ++g) {
        s += ps[(size_t)g * 256];
        q += qs[(size_t)g * 256];
    }
    sbuf[b * C + t] = s;
    const float invn = 1.f / (float)HW, invn2 = invn * invn;
    float v = q * invn - s * s * invn2;
    v = wave_sum(v);
    __shared__ float red[4];
    if ((t & 63) == 0) red[t >> 6] = v;
    __syncthreads();
    if (t == 0) {
        float tr = red[0] + red[1] + red[2] + red[3];
        trbuf[b] = tr;
        strbuf[b] = sqrtf(tr);
    }
}

// ---------------------------------------------------------------------------
// gram split-K: 1-wave blocks, 64x64 tile, fragment-major coalesced loads,
// register dbuf, XCD-pinned. Grid 2240 x 64. launch_bounds(64,1) so the
// double-buffer actually lives in registers (~2x16 b8v + 64 acc VGPRs).
// ---------------------------------------------------------------------------
__global__ __launch_bounds__(64, 1) void k_gram_split(
    const unsigned short* __restrict__ X, float* __restrict__ part) {
    const int bid = blockIdx.x;
    const int x8 = bid & 7;
    const int t8 = bid >> 3;
    const int pairIdx = t8 % 10;
    const int g = (t8 / 10) * 8 + x8;   // 0..223, pinned to XCD x8
    const int b = g & 31;
    const int z = g >> 5;               // 0..6

    int p = pairIdx, tm = 0, rem = 4;
    while (p >= rem) { p -= rem; ++tm; --rem; }
    const int tn = tm + p;

    const int lane = threadIdx.x & 63;
    const int q = lane >> 4, r = lane & 15;
    const int kc0 = z * (KCHUNK / 32);
    const size_t matb = (size_t)b * KC32 * SLAB;

    int oA[4], oB[4];
#pragma unroll
    for (int i = 0; i < 4; ++i) {
        oA[i] = (tm * 64 + i * 16 + r) * 32 + q * 8;
        oB[i] = (tn * 64 + i * 16 + r) * 32 + q * 8;
    }

    f4v acc[4][4] = {};
    b8v fAh[2][4], fAl[2][4], fBh[2][4], fBl[2][4];
#define LDG(buf, kc)                                                     \
    do {                                                                 \
        const size_t sb = matb + (size_t)(kc0 + (kc)) * SLAB;            \
        for (int i = 0; i < 4; ++i) {                                    \
            fAh[buf][i] = *(const b8v*)(X + sb + oA[i]);                 \
            fAl[buf][i] = *(const b8v*)(X + sb + HALF + oA[i]);          \
            fBh[buf][i] = *(const b8v*)(X + sb + oB[i]);                 \
            fBl[buf][i] = *(const b8v*)(X + sb + HALF + oB[i]);          \
        }                                                                \
    } while (0)

    LDG(0, 0);
#pragma unroll
    for (int kc = 0; kc < KCHUNK / 32; ++kc) {
        const int cb = kc & 1, nb = cb ^ 1;
        if (kc < KCHUNK / 32 - 1) LDG(nb, kc + 1);
#pragma unroll
        for (int i = 0; i < 4; ++i)
#pragma unroll
            for (int j = 0; j < 4; ++j) {
                acc[i][j] = __builtin_amdgcn_mfma_f32_16x16x32_bf16(fAh[cb][i], fBh[cb][j], acc[i][j], 0, 0, 0);
                acc[i][j] = __builtin_amdgcn_mfma_f32_16x16x32_bf16(fAh[cb][i], fBl[cb][j], acc[i][j], 0, 0, 0);
                acc[i][j] = __builtin_amdgcn_mfma_f32_16x16x32_bf16(fAl[cb][i], fBh[cb][j], acc[i][j], 0, 0, 0);
            }
    }
#undef LDG

    float* pt = part + (((size_t)pairIdx * BATCH + b) * KSPLIT + z) * 4096;
#pragma unroll
    for (int i = 0; i < 4; ++i)
#pragma unroll
        for (int j = 0; j < 4; ++j)
#pragma unroll
            for (int reg = 0; reg < 4; ++reg) {
                int row = i * 16 + q * 4 + reg;
                int col = j * 16 + r;
                pt[row * 64 + col] = acc[i][j][reg];
            }
}

// ---------------------------------------------------------------------------
// reduce partials -> a and z0 (interleaved fragment-major), mirrored via LDS
// ---------------------------------------------------------------------------
__global__ __launch_bounds__(256) void k_reduce(
    const float* __restrict__ part, const float* __restrict__ sbuf,
    const float* __restrict__ trbuf,
    unsigned short* __restrict__ A, unsigned short* __restrict__ Z) {
    const int b = blockIdx.y;
    int p = blockIdx.x, tm = 0, rem = 4;
    while (p >= rem) { p -= rem; ++tm; --rem; }
    const int tn = tm + p;

    const float* pb = part + ((size_t)blockIdx.x * BATCH + b) * KSPLIT * 4096;
    const int t = threadIdx.x;
    const int row = t >> 2, c0 = (t & 3) * 16;

    float s[16];
#pragma unroll
    for (int u = 0; u < 16; ++u) s[u] = 0.f;
    for (int sp = 0; sp < KSPLIT; ++sp) {
        const float* q4 = pb + sp * 4096 + row * 64 + c0;
#pragma unroll
        for (int u4 = 0; u4 < 4; ++u4) {
            float4 v = *(const float4*)(q4 + u4 * 4);
            s[u4 * 4 + 0] += v.x; s[u4 * 4 + 1] += v.y;
            s[u4 * 4 + 2] += v.z; s[u4 * 4 + 3] += v.w;
        }
    }

    const float invn = 1.f / (float)HW, invn2 = invn * invn;
    const float tr = trbuf[b];
    const int gi = tm * 64 + row;
    const float si = sbuf[b * C + gi];
    const size_t mb = (size_t)b * 8 * SLAB;

    __shared__ unsigned short tAh[64][66], tAl[64][66], tZh[64][66], tZl[64][66];
    unsigned short vAh[16], vAl[16], vZh[16], vZl[16];
#pragma unroll
    for (int u = 0; u < 16; ++u) {
        int gj = tn * 64 + c0 + u;
        float sj = sbuf[b * C + gj];
        float a = (s[u] * invn - si * sj * invn2) / tr;
        split2(a, vAh[u], vAl[u]);
        float zv = ((gi == gj) ? 1.5f : 0.f) - 0.5f * a;
        split2(zv, vZh[u], vZl[u]);
        tAh[row][c0 + u] = vAh[u]; tAl[row][c0 + u] = vAl[u];
        tZh[row][c0 + u] = vZh[u]; tZl[row][c0 + u] = vZl[u];
    }
#pragma unroll
    for (int u4 = 0; u4 < 4; ++u4) {
        const int col0 = tn * 64 + c0 + u4 * 4;
        const size_t off = mb + (size_t)(col0 >> 5) * SLAB + (size_t)gi * 32 + (col0 & 31);
        *(ushort4*)&A[off] = *(ushort4*)&vAh[u4 * 4];
        *(ushort4*)&A[off + HALF] = *(ushort4*)&vAl[u4 * 4];
        *(ushort4*)&Z[off] = *(ushort4*)&vZh[u4 * 4];
        *(ushort4*)&Z[off + HALF] = *(ushort4*)&vZl[u4 * 4];
    }
    if (tm != tn) {
        __syncthreads();
        const int mr = t >> 2, mc0 = (t & 3) * 16;
        const int gim = tn * 64 + mr;
        unsigned short wAh[16], wAl[16], wZh[16], wZl[16];
#pragma unroll
        for (int u = 0; u < 16; ++u) {
            wAh[u] = tAh[mc0 + u][mr]; wAl[u] = tAl[mc0 + u][mr];
            wZh[u] = tZh[mc0 + u][mr]; wZl[u] = tZl[mc0 + u][mr];
        }
#pragma unroll
        for (int u4 = 0; u4 < 4; ++u4) {
            const int col0 = tm * 64 + mc0 + u4 * 4;
            const size_t off = mb + (size_t)(col0 >> 5) * SLAB + (size_t)gim * 32 + (col0 & 31);
            *(ushort4*)&A[off] = *(ushort4*)&wAh[u4 * 4];
            *(ushort4*)&A[off + HALF] = *(ushort4*)&wAl[u4 * 4];
            *(ushort4*)&Z[off] = *(ushort4*)&wZh[u4 * 4];
            *(ushort4*)&Z[off + HALF] = *(ushort4*)&wZl[u4 * 4];
        }
    }
}

// ---------------------------------------------------------------------------
// NS core: one wave, 64x64 tile, K=256, interleaved fragment-major loads,
// register dbuf. No LDS, no barriers. Callers use launch_bounds(64,1) so
// the dbuf (~128 VGPR of fragments) materializes.
// ---------------------------------------------------------------------------
__device__ __forceinline__ void wave_gemm64(
    const unsigned short* __restrict__ A, const unsigned short* __restrict__ B,
    int rowA, int rowB, f4v acc[4][4]) {
    const int lane = threadIdx.x & 63;
    const int q = lane >> 4, r = lane & 15;
    int oA[4], oB[4];
#pragma unroll
    for (int i = 0; i < 4; ++i) {
        oA[i] = (rowA + i * 16 + r) * 32 + q * 8;
        oB[i] = (rowB + i * 16 + r) * 32 + q * 8;
    }
    b8v fAh[2][4], fAl[2][4], fBh[2][4], fBl[2][4];
#define LD(buf, kc)                                              \
    do {                                                         \
        const size_t sb = (size_t)(kc) * SLAB;                   \
        for (int i = 0; i < 4; ++i) {                            \
            fAh[buf][i] = *(const b8v*)(A + sb + oA[i]);         \
            fAl[buf][i] = *(const b8v*)(A + sb + HALF + oA[i]);  \
            fBh[buf][i] = *(const b8v*)(B + sb + oB[i]);         \
            fBl[buf][i] = *(const b8v*)(B + sb + HALF + oB[i]);  \
        }                                                        \
    } while (0)

    LD(0, 0);
#pragma unroll
    for (int kc = 0; kc < 8; ++kc) {
        const int cb = kc & 1, nb = cb ^ 1;
        if (kc < 7) LD(nb, kc + 1);
#pragma unroll
        for (int i = 0; i < 4; ++i)
#pragma unroll
            for (int j = 0; j < 4; ++j) {
                acc[i][j] = __builtin_amdgcn_mfma_f32_16x16x32_bf16(fAh[cb][i], fBh[cb][j], acc[i][j], 0, 0, 0);
                acc[i][j] = __builtin_amdgcn_mfma_f32_16x16x32_bf16(fAh[cb][i], fBl[cb][j], acc[i][j], 0, 0, 0);
                acc[i][j] = __builtin_amdgcn_mfma_f32_16x16x32_bf16(fAl[cb][i], fBh[cb][j], acc[i][j], 0, 0, 0);
            }
    }
#undef LD
}

// store one 64x64 result tile into interleaved fragment-major D (direct)
__device__ __forceinline__ void store_tile_fm(
    unsigned short* __restrict__ D, int tm, int tn, const f4v acc[4][4], bool modeT) {
    const int lane = threadIdx.x & 63, q = lane >> 4, r = lane & 15;
#pragma unroll
    for (int i = 0; i < 4; ++i)
#pragma unroll
        for (int j = 0; j < 4; ++j) {
            const int gj = tn * 64 + j * 16 + r;
            const size_t cbase = (size_t)(gj >> 5) * SLAB + (gj & 31);
#pragma unroll
            for (int reg = 0; reg < 4; ++reg) {
                const int gi = tm * 64 + i * 16 + q * 4 + reg;
                float v = acc[i][j][reg];
                if (modeT) v = ((gi == gj) ? 1.5f : 0.f) - 0.5f * v;
                unsigned short h, l;
                split2(v, h, l);
                D[cbase + (size_t)gi * 32] = h;
                D[cbase + HALF + (size_t)gi * 32] = l;
            }
        }
}

// MODE 0: D = acc ; MODE 1: D = 1.5I - 0.5 acc ; MODE 2: triuvec(acc*sqrt(tr))
// XCD-pinned flat grid: batch b always lands on XCD b%8.
template <int MODE>
__global__ __launch_bounds__(64, 1) void k_t64(
    const unsigned short* __restrict__ A, const unsigned short* __restrict__ B,
    unsigned short* __restrict__ D, float* __restrict__ outF,
    const float* __restrict__ strbuf) {
    const int bid = blockIdx.x;
    const int x8 = bid & 7;
    const int w = bid >> 3;
    int b, tm = 0, tn = 0;
    if (MODE == 2) {
        b = x8 + 8 * (w / 10);
        int p = w % 10, rem = 4;
        while (p >= rem) { p -= rem; ++tm; --rem; }
        tn = tm + p;
    } else {
        b = x8 + 8 * (w >> 4);
        const int tile = w & 15;
        tm = tile >> 2; tn = tile & 3;
    }
    const size_t mo = (size_t)b * 8 * SLAB;
    f4v acc[4][4] = {};
    wave_gemm64(A + mo, B + mo, tm * 64, tn * 64, acc);

    if (MODE == 2) {
        const int lane = threadIdx.x & 63, q = lane >> 4, r = lane & 15;
        const float sc = strbuf[b];
#pragma unroll
        for (int i = 0; i < 4; ++i)
#pragma unroll
            for (int j = 0; j < 4; ++j) {
                const int gj = tn * 64 + j * 16 + r;
#pragma unroll
                for (int reg = 0; reg < 4; ++reg) {
                    const int gi = tm * 64 + i * 16 + q * 4 + reg;
                    if (gj >= gi)
                        outF[(size_t)b * OUTROW + (size_t)(gi * C - (gi * (gi - 1)) / 2) +
                             (gj - gi)] = acc[i][j][reg] * sc;
                }
            }
    } else {
        store_tile_fm(D + mo, tm, tn, acc, MODE == 1);
    }
}

// fused Ynew = Y@T, Znew = T@Z ; XCD-pinned flat grid (1024 blocks)
__global__ __launch_bounds__(64, 1) void k_yz64(
    const unsigned short* __restrict__ Y, const unsigned short* __restrict__ T,
    const unsigned short* __restrict__ Z,
    unsigned short* __restrict__ Yn, unsigned short* __restrict__ Zn) {
    const int bid = blockIdx.x;
    const int x8 = bid & 7;
    const int w = bid >> 3;                 // 0..127
    const int b = x8 + 8 * ((w >> 4) & 3);
    const int zz = w >> 6;                  // 0: Y@T, 1: T@Z
    const int tile = w & 15;
    const int tm = tile >> 2, tn = tile & 3;

    const unsigned short* Am = zz ? T : Y;
    const unsigned short* Bm = zz ? Z : T;
    unsigned short* Dm = zz ? Zn : Yn;

    const size_t mo = (size_t)b * 8 * SLAB;
    f4v acc[4][4] = {};
    wave_gemm64(Am + mo, Bm + mo, tm * 64, tn * 64, acc);
    store_tile_fm(Dm + mo, tm, tn, acc, false);
}

// ---------------------------------------------------------------------------
extern "C" void kernel_launch(void* const* d_in, const int* in_sizes, int n_in,
                              void* d_out, int out_size, void* d_ws, size_t ws_size,
                              hipStream_t stream) {
    const float* x = (const float*)d_in[0];
    float* out = (float*)d_out;

    unsigned short* W = (unsigned short*)d_ws;
    const size_t XS = (size_t)BATCH * KC32 * SLAB;   // interleaved X shorts
    const size_t MS = (size_t)BATCH * 8 * SLAB;      // one interleaved matrix set
    unsigned short* X = W;
    float* sbuf = (float*)(X + XS);
    float* trbuf = sbuf + BATCH * C;
    float* strbuf = trbuf + BATCH;
    unsigned short* P = (unsigned short*)(strbuf + BATCH);
    unsigned short* PA = P + 0 * MS;
    unsigned short* PB = P + 1 * MS;
    unsigned short* PC = P + 2 * MS;
    unsigned short* PD = P + 3 * MS;
    unsigned short* PE = P + 4 * MS;
    // fp32 gram partials alias PC.. (dead until Y0 is written)
    float* part = (float*)PC;                         // 10*32*7*4096 floats
    // prep sum partials alias PA (dead until k_reduce writes it)
    float* psum = (float*)PA;                         // 32*49*256 floats
    float* qsum = psum + (size_t)BATCH * KCG * 256;

    k_prep<<<dim3(BATCH * KCG), 256, 0, stream>>>(x, X, psum, qsum);
    k_tr<<<dim3(BATCH), 256, 0, stream>>>(psum, qsum, sbuf, trbuf, strbuf);
    k_gram_split<<<dim3(10 * BATCH * KSPLIT), 64, 0, stream>>>(X, part);
    k_reduce<<<dim3(10, BATCH), 256, 0, stream>>>(part, sbuf, trbuf, PA, PB);

    dim3 g512(512);
    // Y0 = a @ z0 -> PC
    k_t64<0><<<g512, 64, 0, stream>>>(PA, PB, PC, nullptr, strbuf);
    // it0: T0 = 1.5I - 0.5 Z0@Y0 = PB@PC -> PD ; Y1 = PC@PD -> PA ; Z1 = PD@PB -> PE
    k_t64<1><<<g512, 64, 0, stream>>>(PB, PC, PD, nullptr, strbuf);
    k_yz64<<<dim3(1024), 64, 0, stream>>>(PC, PD, PB, PA, PE);
    // it1: T1 = PE@PA -> PB ; Y2 = PA@PB -> PC ; Z2 = PB@PE -> PD
    k_t64<1><<<g512, 64, 0, stream>>>(PE, PA, PB, nullptr, strbuf);
    k_yz64<<<dim3(1024), 64, 0, stream>>>(PA, PB, PE, PC, PD);
    // it2: T2 = PD@PC -> PA ; Y3 = PC@PA -> PB ; Z3 = PA@PD -> PE
    k_t64<1><<<g512, 64, 0, stream>>>(PD, PC, PA, nullptr, strbuf);
    k_yz64<<<dim3(1024), 64, 0, stream>>>(PC, PA, PD, PB, PE);
    // it3: T3 = PE@PB -> PC ; out = triuvec((PB@PC) * sqrt(tr))
    k_t64<1><<<g512, 64, 0, stream>>>(PE, PB, PC, nullptr, strbuf);
    k_t64<2><<<dim3(320), 64, 0, stream>>>(PB, PC, nullptr, out, strbuf);
}

// Round 7
// 349.137 us; speedup vs baseline: 1.2007x; 1.0439x over previous
//
#include <hip/hip_runtime.h>
#include <hip/hip_bf16.h>
#include <math.h>

#define BATCH 32
#define C 256
#define HW 3136
#define OUTROW 32896
#define KSPLIT 7
#define KCHUNK 448   // HW / KSPLIT
#define KC32 98      // HW / 32
#define KCG 49       // kc-pair groups per batch
#define SLAB 16384   // shorts per kc slab (hi 8192 + lo 8192 interleaved)
#define HALF 8192

// Interleaved fragment-major layouts (shorts):
//   X slab s = b*98 + kc :  X[s*SLAB + row*32 + (k&31)]        (hi)
//                           X[s*SLAB + HALF + row*32 + (k&31)] (lo)
//   M slab s = b*8 + kc  :  same, 256x256 matrices, 8 slabs each.

typedef __bf16 b8v __attribute__((ext_vector_type(8)));
typedef float  f4v __attribute__((ext_vector_type(4)));
typedef unsigned short u16x8 __attribute__((ext_vector_type(8)));

__device__ __forceinline__ unsigned short f2bf(float f) {
    union { float f; unsigned u; } v; v.f = f;
    unsigned r = v.u + 0x7FFFu + ((v.u >> 16) & 1u);
    return (unsigned short)(r >> 16);
}
__device__ __forceinline__ float bf2f(unsigned short h) {
    union { unsigned u; float f; } v; v.u = ((unsigned)h) << 16; return v.f;
}
__device__ __forceinline__ void split2(float x, unsigned short& h, unsigned short& l) {
    h = f2bf(x);
    l = f2bf(x - bf2f(h));
}

__device__ __forceinline__ float wave_sum(float v) {
    for (int o = 32; o; o >>= 1) v += __shfl_down(v, o, 64);
    return v;
}

// ---------------------------------------------------------------------------
// prep: x -> hi/lo bf16 split, interleaved fragment-major X layout.
// ---------------------------------------------------------------------------
__global__ __launch_bounds__(256) void k_prep(const float* __restrict__ x,
                                              unsigned short* __restrict__ X,
                                              float* __restrict__ psum,
                                              float* __restrict__ qsum) {
    const int blk = blockIdx.x;                 // b*KCG + g
    const int b = blk / KCG;
    const int g = blk - b * KCG;
    const int kc0 = g * 2;
    const int t = threadIdx.x;
    const int lane4 = t & 3;                    // 4 lanes per row, 16 floats each
    const int rowoff = t >> 2;                  // 0..63
    const int ko = lane4 * 8;

    const float* xb = x + (size_t)b * C * HW + (size_t)kc0 * 32 + ko;
    unsigned short* s0 = X + (size_t)(b * KC32 + kc0) * SLAB + ko;
    unsigned short* s1 = s0 + SLAB;
    float* ps = psum + (size_t)blk * 256;
    float* qs = qsum + (size_t)blk * 256;

#pragma unroll
    for (int it = 0; it < 4; ++it) {
        const int row = it * 64 + rowoff;
        const float* src = xb + (size_t)row * HW;
        float4 v0 = *(const float4*)(src);
        float4 v1 = *(const float4*)(src + 4);
        float4 v2 = *(const float4*)(src + 32);
        float4 v3 = *(const float4*)(src + 36);
        float va[8] = { v0.x, v0.y, v0.z, v0.w, v1.x, v1.y, v1.z, v1.w };
        float vb[8] = { v2.x, v2.y, v2.z, v2.w, v3.x, v3.y, v3.z, v3.w };
        unsigned short ha[8], la[8], hb[8], lb[8];
        float s = 0.f, q = 0.f;
#pragma unroll
        for (int j = 0; j < 8; ++j) {
            split2(va[j], ha[j], la[j]);
            split2(vb[j], hb[j], lb[j]);
            s += va[j] + vb[j];
            q = fmaf(va[j], va[j], q);
            q = fmaf(vb[j], vb[j], q);
        }
        *(u16x8*)(s0 + row * 32) = *(u16x8*)ha;
        *(u16x8*)(s0 + HALF + row * 32) = *(u16x8*)la;
        *(u16x8*)(s1 + row * 32) = *(u16x8*)hb;
        *(u16x8*)(s1 + HALF + row * 32) = *(u16x8*)lb;
        s += __shfl_xor(s, 1, 64);
        s += __shfl_xor(s, 2, 64);
        q += __shfl_xor(q, 1, 64);
        q += __shfl_xor(q, 2, 64);
        if (lane4 == 0) { ps[row] = s; qs[row] = q; }
    }
}

// reduce per-kcg partials -> sbuf (row sums) + trace
__global__ __launch_bounds__(256) void k_tr(const float* __restrict__ psum,
                                            const float* __restrict__ qsum,
                                            float* __restrict__ sbuf,
                                            float* __restrict__ trbuf,
                                            float* __restrict__ strbuf) {
    const int b = blockIdx.x, t = threadIdx.x;
    const float* ps = psum + (size_t)b * KCG * 256 + t;
    const float* qs = qsum + (size_t)b * KCG * 256 + t;
    float s = 0.f, q = 0.f;
#pragma unroll 7
    for (int g = 0; g < KCG; ++g) {
        s += ps[(size_t)g * 256];
        q += qs[(size_t)g * 256];
    }
    sbuf[b * C + t] = s;
    const float invn = 1.f / (float)HW, invn2 = invn * invn;
    float v = q * invn - s * s * invn2;
    v = wave_sum(v);
    __shared__ float red[4];
    if ((t & 63) == 0) red[t >> 6] = v;
    __syncthreads();
    if (t == 0) {
        float tr = red[0] + red[1] + red[2] + red[3];
        trbuf[b] = tr;
        strbuf[b] = sqrtf(tr);
    }
}

// ---------------------------------------------------------------------------
// gram split-K: 1-wave blocks, 64x64 tile, fragment-major coalesced loads,
// register dbuf, XCD-pinned. Grid 2240 x 64.
// ---------------------------------------------------------------------------
__global__ __launch_bounds__(64, 1) void k_gram_split(
    const unsigned short* __restrict__ X, float* __restrict__ part) {
    const int bid = blockIdx.x;
    const int x8 = bid & 7;
    const int t8 = bid >> 3;
    const int pairIdx = t8 % 10;
    const int g = (t8 / 10) * 8 + x8;   // 0..223, pinned to XCD x8
    const int b = g & 31;
    const int z = g >> 5;               // 0..6

    int p = pairIdx, tm = 0, rem = 4;
    while (p >= rem) { p -= rem; ++tm; --rem; }
    const int tn = tm + p;

    const int lane = threadIdx.x & 63;
    const int q = lane >> 4, r = lane & 15;
    const int kc0 = z * (KCHUNK / 32);
    const size_t matb = (size_t)b * KC32 * SLAB;

    int oA[4], oB[4];
#pragma unroll
    for (int i = 0; i < 4; ++i) {
        oA[i] = (tm * 64 + i * 16 + r) * 32 + q * 8;
        oB[i] = (tn * 64 + i * 16 + r) * 32 + q * 8;
    }

    f4v acc[4][4] = {};
    b8v fAh[2][4], fAl[2][4], fBh[2][4], fBl[2][4];
#define LDG(buf, kc)                                                     \
    do {                                                                 \
        const size_t sb = matb + (size_t)(kc0 + (kc)) * SLAB;            \
        for (int i = 0; i < 4; ++i) {                                    \
            fAh[buf][i] = *(const b8v*)(X + sb + oA[i]);                 \
            fAl[buf][i] = *(const b8v*)(X + sb + HALF + oA[i]);          \
            fBh[buf][i] = *(const b8v*)(X + sb + oB[i]);                 \
            fBl[buf][i] = *(const b8v*)(X + sb + HALF + oB[i]);          \
        }                                                                \
    } while (0)

    LDG(0, 0);
#pragma unroll
    for (int kc = 0; kc < KCHUNK / 32; ++kc) {
        const int cb = kc & 1, nb = cb ^ 1;
        if (kc < KCHUNK / 32 - 1) LDG(nb, kc + 1);
#pragma unroll
        for (int i = 0; i < 4; ++i)
#pragma unroll
            for (int j = 0; j < 4; ++j) {
                acc[i][j] = __builtin_amdgcn_mfma_f32_16x16x32_bf16(fAh[cb][i], fBh[cb][j], acc[i][j], 0, 0, 0);
                acc[i][j] = __builtin_amdgcn_mfma_f32_16x16x32_bf16(fAh[cb][i], fBl[cb][j], acc[i][j], 0, 0, 0);
                acc[i][j] = __builtin_amdgcn_mfma_f32_16x16x32_bf16(fAl[cb][i], fBh[cb][j], acc[i][j], 0, 0, 0);
            }
    }
#undef LDG

    float* pt = part + (((size_t)pairIdx * BATCH + b) * KSPLIT + z) * 4096;
#pragma unroll
    for (int i = 0; i < 4; ++i)
#pragma unroll
        for (int j = 0; j < 4; ++j)
#pragma unroll
            for (int reg = 0; reg < 4; ++reg) {
                int row = i * 16 + q * 4 + reg;
                int col = j * 16 + r;
                pt[row * 64 + col] = acc[i][j][reg];
            }
}

// ---------------------------------------------------------------------------
// reduce partials -> a and z0 (interleaved fragment-major), mirrored via LDS
// ---------------------------------------------------------------------------
__global__ __launch_bounds__(256) void k_reduce(
    const float* __restrict__ part, const float* __restrict__ sbuf,
    const float* __restrict__ trbuf,
    unsigned short* __restrict__ A, unsigned short* __restrict__ Z) {
    const int b = blockIdx.y;
    int p = blockIdx.x, tm = 0, rem = 4;
    while (p >= rem) { p -= rem; ++tm; --rem; }
    const int tn = tm + p;

    const float* pb = part + ((size_t)blockIdx.x * BATCH + b) * KSPLIT * 4096;
    const int t = threadIdx.x;
    const int row = t >> 2, c0 = (t & 3) * 16;

    float s[16];
#pragma unroll
    for (int u = 0; u < 16; ++u) s[u] = 0.f;
    for (int sp = 0; sp < KSPLIT; ++sp) {
        const float* q4 = pb + sp * 4096 + row * 64 + c0;
#pragma unroll
        for (int u4 = 0; u4 < 4; ++u4) {
            float4 v = *(const float4*)(q4 + u4 * 4);
            s[u4 * 4 + 0] += v.x; s[u4 * 4 + 1] += v.y;
            s[u4 * 4 + 2] += v.z; s[u4 * 4 + 3] += v.w;
        }
    }

    const float invn = 1.f / (float)HW, invn2 = invn * invn;
    const float tr = trbuf[b];
    const int gi = tm * 64 + row;
    const float si = sbuf[b * C + gi];
    const size_t mb = (size_t)b * 8 * SLAB;

    __shared__ unsigned short tAh[64][66], tAl[64][66], tZh[64][66], tZl[64][66];
    unsigned short vAh[16], vAl[16], vZh[16], vZl[16];
#pragma unroll
    for (int u = 0; u < 16; ++u) {
        int gj = tn * 64 + c0 + u;
        float sj = sbuf[b * C + gj];
        float a = (s[u] * invn - si * sj * invn2) / tr;
        split2(a, vAh[u], vAl[u]);
        float zv = ((gi == gj) ? 1.5f : 0.f) - 0.5f * a;
        split2(zv, vZh[u], vZl[u]);
        tAh[row][c0 + u] = vAh[u]; tAl[row][c0 + u] = vAl[u];
        tZh[row][c0 + u] = vZh[u]; tZl[row][c0 + u] = vZl[u];
    }
#pragma unroll
    for (int u4 = 0; u4 < 4; ++u4) {
        const int col0 = tn * 64 + c0 + u4 * 4;
        const size_t off = mb + (size_t)(col0 >> 5) * SLAB + (size_t)gi * 32 + (col0 & 31);
        *(ushort4*)&A[off] = *(ushort4*)&vAh[u4 * 4];
        *(ushort4*)&A[off + HALF] = *(ushort4*)&vAl[u4 * 4];
        *(ushort4*)&Z[off] = *(ushort4*)&vZh[u4 * 4];
        *(ushort4*)&Z[off + HALF] = *(ushort4*)&vZl[u4 * 4];
    }
    if (tm != tn) {
        __syncthreads();
        const int mr = t >> 2, mc0 = (t & 3) * 16;
        const int gim = tn * 64 + mr;
        unsigned short wAh[16], wAl[16], wZh[16], wZl[16];
#pragma unroll
        for (int u = 0; u < 16; ++u) {
            wAh[u] = tAh[mc0 + u][mr]; wAl[u] = tAl[mc0 + u][mr];
            wZh[u] = tZh[mc0 + u][mr]; wZl[u] = tZl[mc0 + u][mr];
        }
#pragma unroll
        for (int u4 = 0; u4 < 4; ++u4) {
            const int col0 = tm * 64 + mc0 + u4 * 4;
            const size_t off = mb + (size_t)(col0 >> 5) * SLAB + (size_t)gim * 32 + (col0 & 31);
            *(ushort4*)&A[off] = *(ushort4*)&wAh[u4 * 4];
            *(ushort4*)&A[off + HALF] = *(ushort4*)&wAl[u4 * 4];
            *(ushort4*)&Z[off] = *(ushort4*)&wZh[u4 * 4];
            *(ushort4*)&Z[off + HALF] = *(ushort4*)&wZl[u4 * 4];
        }
    }
}

// ---------------------------------------------------------------------------
// NS core: one wave, 32x32 tile, K=256, interleaved fragment-major loads,
// register dbuf. 4x the blocks of the 64-tile version -> 2-4 waves/SIMD TLP.
// Accumulation order per output element identical to the 64-tile version.
// ---------------------------------------------------------------------------
__device__ __forceinline__ void wave_gemm32(
    const unsigned short* __restrict__ A, const unsigned short* __restrict__ B,
    int rowA, int rowB, f4v acc[2][2]) {
    const int lane = threadIdx.x & 63;
    const int q = lane >> 4, r = lane & 15;
    int oA[2], oB[2];
#pragma unroll
    for (int i = 0; i < 2; ++i) {
        oA[i] = (rowA + i * 16 + r) * 32 + q * 8;
        oB[i] = (rowB + i * 16 + r) * 32 + q * 8;
    }
    b8v fAh[2][2], fAl[2][2], fBh[2][2], fBl[2][2];
#define LD(buf, kc)                                              \
    do {                                                         \
        const size_t sb = (size_t)(kc) * SLAB;                   \
        for (int i = 0; i < 2; ++i) {                            \
            fAh[buf][i] = *(const b8v*)(A + sb + oA[i]);         \
            fAl[buf][i] = *(const b8v*)(A + sb + HALF + oA[i]);  \
            fBh[buf][i] = *(const b8v*)(B + sb + oB[i]);         \
            fBl[buf][i] = *(const b8v*)(B + sb + HALF + oB[i]);  \
        }                                                        \
    } while (0)

    LD(0, 0);
#pragma unroll
    for (int kc = 0; kc < 8; ++kc) {
        const int cb = kc & 1, nb = cb ^ 1;
        if (kc < 7) LD(nb, kc + 1);
#pragma unroll
        for (int i = 0; i < 2; ++i)
#pragma unroll
            for (int j = 0; j < 2; ++j) {
                acc[i][j] = __builtin_amdgcn_mfma_f32_16x16x32_bf16(fAh[cb][i], fBh[cb][j], acc[i][j], 0, 0, 0);
                acc[i][j] = __builtin_amdgcn_mfma_f32_16x16x32_bf16(fAh[cb][i], fBl[cb][j], acc[i][j], 0, 0, 0);
                acc[i][j] = __builtin_amdgcn_mfma_f32_16x16x32_bf16(fAl[cb][i], fBh[cb][j], acc[i][j], 0, 0, 0);
            }
    }
#undef LD
}

// store one 32x32 result tile into interleaved fragment-major D (direct)
__device__ __forceinline__ void store_tile32(
    unsigned short* __restrict__ D, int tm, int tn, const f4v acc[2][2], bool modeT) {
    const int lane = threadIdx.x & 63, q = lane >> 4, r = lane & 15;
#pragma unroll
    for (int i = 0; i < 2; ++i)
#pragma unroll
        for (int j = 0; j < 2; ++j) {
            const int gj = tn * 32 + j * 16 + r;
            const size_t cbase = (size_t)(gj >> 5) * SLAB + (gj & 31);
#pragma unroll
            for (int reg = 0; reg < 4; ++reg) {
                const int gi = tm * 32 + i * 16 + q * 4 + reg;
                float v = acc[i][j][reg];
                if (modeT) v = ((gi == gj) ? 1.5f : 0.f) - 0.5f * v;
                unsigned short h, l;
                split2(v, h, l);
                D[cbase + (size_t)gi * 32] = h;
                D[cbase + HALF + (size_t)gi * 32] = l;
            }
        }
}

// MODE 0: D = acc ; MODE 1: D = 1.5I - 0.5 acc ; MODE 2: triuvec(acc*sqrt(tr))
// XCD-pinned flat grid: batch b always lands on XCD b%8.
// MODE 0/1: grid 2048 (8 XCD x 4 b x 64 tiles). MODE 2: 1152 (8 x 4 x 36 tri).
template <int MODE>
__global__ __launch_bounds__(64, 1) void k_t64(
    const unsigned short* __restrict__ A, const unsigned short* __restrict__ B,
    unsigned short* __restrict__ D, float* __restrict__ outF,
    const float* __restrict__ strbuf) {
    const int bid = blockIdx.x;
    const int x8 = bid & 7;
    const int w = bid >> 3;
    int b, tm = 0, tn = 0;
    if (MODE == 2) {
        b = x8 + 8 * (w / 36);
        int p = w % 36, rem = 8;
        while (p >= rem) { p -= rem; ++tm; --rem; }
        tn = tm + p;
    } else {
        b = x8 + 8 * (w >> 6);
        const int tile = w & 63;
        tm = tile >> 3; tn = tile & 7;
    }
    const size_t mo = (size_t)b * 8 * SLAB;
    f4v acc[2][2] = {};
    wave_gemm32(A + mo, B + mo, tm * 32, tn * 32, acc);

    if (MODE == 2) {
        const int lane = threadIdx.x & 63, q = lane >> 4, r = lane & 15;
        const float sc = strbuf[b];
#pragma unroll
        for (int i = 0; i < 2; ++i)
#pragma unroll
            for (int j = 0; j < 2; ++j) {
                const int gj = tn * 32 + j * 16 + r;
#pragma unroll
                for (int reg = 0; reg < 4; ++reg) {
                    const int gi = tm * 32 + i * 16 + q * 4 + reg;
                    if (gj >= gi)
                        outF[(size_t)b * OUTROW + (size_t)(gi * C - (gi * (gi - 1)) / 2) +
                             (gj - gi)] = acc[i][j][reg] * sc;
                }
            }
    } else {
        store_tile32(D + mo, tm, tn, acc, MODE == 1);
    }
}

// fused Ynew = Y@T, Znew = T@Z ; XCD-pinned flat grid (4096 blocks)
__global__ __launch_bounds__(64, 1) void k_yz64(
    const unsigned short* __restrict__ Y, const unsigned short* __restrict__ T,
    const unsigned short* __restrict__ Z,
    unsigned short* __restrict__ Yn, unsigned short* __restrict__ Zn) {
    const int bid = blockIdx.x;
    const int x8 = bid & 7;
    const int w = bid >> 3;                 // 0..511
    const int zz = w >> 8;                  // 0: Y@T, 1: T@Z
    const int ww = w & 255;
    const int b = x8 + 8 * (ww >> 6);
    const int tile = ww & 63;
    const int tm = tile >> 3, tn = tile & 7;

    const unsigned short* Am = zz ? T : Y;
    const unsigned short* Bm = zz ? Z : T;
    unsigned short* Dm = zz ? Zn : Yn;

    const size_t mo = (size_t)b * 8 * SLAB;
    f4v acc[2][2] = {};
    wave_gemm32(Am + mo, Bm + mo, tm * 32, tn * 32, acc);
    store_tile32(Dm + mo, tm, tn, acc, false);
}

// ---------------------------------------------------------------------------
extern "C" void kernel_launch(void* const* d_in, const int* in_sizes, int n_in,
                              void* d_out, int out_size, void* d_ws, size_t ws_size,
                              hipStream_t stream) {
    const float* x = (const float*)d_in[0];
    float* out = (float*)d_out;

    unsigned short* W = (unsigned short*)d_ws;
    const size_t XS = (size_t)BATCH * KC32 * SLAB;   // interleaved X shorts
    const size_t MS = (size_t)BATCH * 8 * SLAB;      // one interleaved matrix set
    unsigned short* X = W;
    float* sbuf = (float*)(X + XS);
    float* trbuf = sbuf + BATCH * C;
    float* strbuf = trbuf + BATCH;
    unsigned short* P = (unsigned short*)(strbuf + BATCH);
    unsigned short* PA = P + 0 * MS;
    unsigned short* PB = P + 1 * MS;
    unsigned short* PC = P + 2 * MS;
    unsigned short* PD = P + 3 * MS;
    unsigned short* PE = P + 4 * MS;
    // fp32 gram partials alias PC.. (dead until Y0 is written)
    float* part = (float*)PC;                         // 10*32*7*4096 floats
    // prep sum partials alias PA (dead until k_reduce writes it)
    float* psum = (float*)PA;                         // 32*49*256 floats
    float* qsum = psum + (size_t)BATCH * KCG * 256;

    k_prep<<<dim3(BATCH * KCG), 256, 0, stream>>>(x, X, psum, qsum);
    k_tr<<<dim3(BATCH), 256, 0, stream>>>(psum, qsum, sbuf, trbuf, strbuf);
    k_gram_split<<<dim3(10 * BATCH * KSPLIT), 64, 0, stream>>>(X, part);
    k_reduce<<<dim3(10, BATCH), 256, 0, stream>>>(part, sbuf, trbuf, PA, PB);

    dim3 g2048(2048);
    // Y0 = a @ z0 -> PC
    k_t64<0><<<g2048, 64, 0, stream>>>(PA, PB, PC, nullptr, strbuf);
    // it0: T0 = 1.5I - 0.5 Z0@Y0 = PB@PC -> PD ; Y1 = PC@PD -> PA ; Z1 = PD@PB -> PE
    k_t64<1><<<g2048, 64, 0, stream>>>(PB, PC, PD, nullptr, strbuf);
    k_yz64<<<dim3(4096), 64, 0, stream>>>(PC, PD, PB, PA, PE);
    // it1: T1 = PE@PA -> PB ; Y2 = PA@PB -> PC ; Z2 = PB@PE -> PD
    k_t64<1><<<g2048, 64, 0, stream>>>(PE, PA, PB, nullptr, strbuf);
    k_yz64<<<dim3(4096), 64, 0, stream>>>(PA, PB, PE, PC, PD);
    // it2: T2 = PD@PC -> PA ; Y3 = PC@PA -> PB ; Z3 = PA@PD -> PE
    k_t64<1><<<g2048, 64, 0, stream>>>(PD, PC, PA, nullptr, strbuf);
    k_yz64<<<dim3(4096), 64, 0, stream>>>(PC, PA, PD, PB, PE);
    // it3: T3 = PE@PB -> PC ; out = triuvec((PB@PC) * sqrt(tr))
    k_t64<1><<<g2048, 64, 0, stream>>>(PE, PB, PC, nullptr, strbuf);
    k_t64<2><<<dim3(1152), 64, 0, stream>>>(PB, PC, nullptr, out, strbuf);
}

// Round 8
// 347.225 us; speedup vs baseline: 1.2073x; 1.0055x over previous
//
#include <hip/hip_runtime.h>
#include <hip/hip_bf16.h>
#include <math.h>

#define BATCH 32
#define C 256
#define HW 3136
#define OUTROW 32896
#define KSPLIT 7
#define KCHUNK 448   // HW / KSPLIT
#define KC32 98      // HW / 32
#define KCG 49       // kc-pair groups per batch
#define SLAB 16384   // shorts per kc slab (hi 8192 + lo 8192 interleaved)
#define HALF 8192

// Interleaved fragment-major layouts (shorts):
//   X slab s = b*98 + kc :  X[s*SLAB + row*32 + (k&31)]        (hi)
//                           X[s*SLAB + HALF + row*32 + (k&31)] (lo)
//   M slab s = b*8 + kc  :  same, 256x256 matrices, 8 slabs each.

typedef __bf16 b8v __attribute__((ext_vector_type(8)));
typedef float  f4v __attribute__((ext_vector_type(4)));
typedef unsigned short u16x8 __attribute__((ext_vector_type(8)));

__device__ __forceinline__ unsigned short f2bf(float f) {
    union { float f; unsigned u; } v; v.f = f;
    unsigned r = v.u + 0x7FFFu + ((v.u >> 16) & 1u);
    return (unsigned short)(r >> 16);
}
__device__ __forceinline__ float bf2f(unsigned short h) {
    union { unsigned u; float f; } v; v.u = ((unsigned)h) << 16; return v.f;
}
__device__ __forceinline__ void split2(float x, unsigned short& h, unsigned short& l) {
    h = f2bf(x);
    l = f2bf(x - bf2f(h));
}

__device__ __forceinline__ float wave_sum(float v) {
    for (int o = 32; o; o >>= 1) v += __shfl_down(v, o, 64);
    return v;
}

// ---------------------------------------------------------------------------
// prep: x -> hi/lo bf16 split, interleaved fragment-major X layout.
// Burst-load all 4 row-iterations first (64 VGPRs of payload, 16 loads in
// flight), then convert+store: separates each wave's read burst from its
// write burst. launch_bounds(256,2) -> VGPR cap 128 so the burst fits.
// ---------------------------------------------------------------------------
__global__ __launch_bounds__(256, 2) void k_prep(const float* __restrict__ x,
                                                 unsigned short* __restrict__ X,
                                                 float* __restrict__ psum,
                                                 float* __restrict__ qsum) {
    const int blk = blockIdx.x;                 // b*KCG + g
    const int b = blk / KCG;
    const int g = blk - b * KCG;
    const int kc0 = g * 2;
    const int t = threadIdx.x;
    const int lane4 = t & 3;                    // 4 lanes per row, 16 floats each
    const int rowoff = t >> 2;                  // 0..63
    const int ko = lane4 * 8;

    const float* xb = x + (size_t)b * C * HW + (size_t)kc0 * 32 + ko;
    unsigned short* s0 = X + (size_t)(b * KC32 + kc0) * SLAB + ko;
    unsigned short* s1 = s0 + SLAB;
    float* ps = psum + (size_t)blk * 256;
    float* qs = qsum + (size_t)blk * 256;

    float4 v[4][4];
#pragma unroll
    for (int it = 0; it < 4; ++it) {
        const float* src = xb + (size_t)(it * 64 + rowoff) * HW;
        v[it][0] = *(const float4*)(src);
        v[it][1] = *(const float4*)(src + 4);
        v[it][2] = *(const float4*)(src + 32);
        v[it][3] = *(const float4*)(src + 36);
    }

#pragma unroll
    for (int it = 0; it < 4; ++it) {
        const int row = it * 64 + rowoff;
        float va[8] = { v[it][0].x, v[it][0].y, v[it][0].z, v[it][0].w,
                        v[it][1].x, v[it][1].y, v[it][1].z, v[it][1].w };
        float vb[8] = { v[it][2].x, v[it][2].y, v[it][2].z, v[it][2].w,
                        v[it][3].x, v[it][3].y, v[it][3].z, v[it][3].w };
        unsigned short ha[8], la[8], hb[8], lb[8];
        float s = 0.f, q = 0.f;
#pragma unroll
        for (int j = 0; j < 8; ++j) {
            split2(va[j], ha[j], la[j]);
            split2(vb[j], hb[j], lb[j]);
            s += va[j] + vb[j];
            q = fmaf(va[j], va[j], q);
            q = fmaf(vb[j], vb[j], q);
        }
        *(u16x8*)(s0 + row * 32) = *(u16x8*)ha;
        *(u16x8*)(s0 + HALF + row * 32) = *(u16x8*)la;
        *(u16x8*)(s1 + row * 32) = *(u16x8*)hb;
        *(u16x8*)(s1 + HALF + row * 32) = *(u16x8*)lb;
        s += __shfl_xor(s, 1, 64);
        s += __shfl_xor(s, 2, 64);
        q += __shfl_xor(q, 1, 64);
        q += __shfl_xor(q, 2, 64);
        if (lane4 == 0) { ps[row] = s; qs[row] = q; }
    }
}

// reduce per-kcg partials -> sbuf (row sums) + trace
__global__ __launch_bounds__(256) void k_tr(const float* __restrict__ psum,
                                            const float* __restrict__ qsum,
                                            float* __restrict__ sbuf,
                                            float* __restrict__ trbuf,
                                            float* __restrict__ strbuf) {
    const int b = blockIdx.x, t = threadIdx.x;
    const float* ps = psum + (size_t)b * KCG * 256 + t;
    const float* qs = qsum + (size_t)b * KCG * 256 + t;
    float s = 0.f, q = 0.f;
#pragma unroll 7
    for (int g = 0; g < KCG; ++g) {
        s += ps[(size_t)g * 256];
        q += qs[(size_t)g * 256];
    }
    sbuf[b * C + t] = s;
    const float invn = 1.f / (float)HW, invn2 = invn * invn;
    float v = q * invn - s * s * invn2;
    v = wave_sum(v);
    __shared__ float red[4];
    if ((t & 63) == 0) red[t >> 6] = v;
    __syncthreads();
    if (t == 0) {
        float tr = red[0] + red[1] + red[2] + red[3];
        trbuf[b] = tr;
        strbuf[b] = sqrtf(tr);
    }
}

// ---------------------------------------------------------------------------
// gram split-K: 1-wave blocks, 64x64 tile, fragment-major coalesced loads,
// register dbuf, XCD-pinned. Grid 2240 x 64.
// ---------------------------------------------------------------------------
__global__ __launch_bounds__(64, 1) void k_gram_split(
    const unsigned short* __restrict__ X, float* __restrict__ part) {
    const int bid = blockIdx.x;
    const int x8 = bid & 7;
    const int t8 = bid >> 3;
    const int pairIdx = t8 % 10;
    const int g = (t8 / 10) * 8 + x8;   // 0..223, pinned to XCD x8
    const int b = g & 31;
    const int z = g >> 5;               // 0..6

    int p = pairIdx, tm = 0, rem = 4;
    while (p >= rem) { p -= rem; ++tm; --rem; }
    const int tn = tm + p;

    const int lane = threadIdx.x & 63;
    const int q = lane >> 4, r = lane & 15;
    const int kc0 = z * (KCHUNK / 32);
    const size_t matb = (size_t)b * KC32 * SLAB;

    int oA[4], oB[4];
#pragma unroll
    for (int i = 0; i < 4; ++i) {
        oA[i] = (tm * 64 + i * 16 + r) * 32 + q * 8;
        oB[i] = (tn * 64 + i * 16 + r) * 32 + q * 8;
    }

    f4v acc[4][4] = {};
    b8v fAh[2][4], fAl[2][4], fBh[2][4], fBl[2][4];
#define LDG(buf, kc)                                                     \
    do {                                                                 \
        const size_t sb = matb + (size_t)(kc0 + (kc)) * SLAB;            \
        for (int i = 0; i < 4; ++i) {                                    \
            fAh[buf][i] = *(const b8v*)(X + sb + oA[i]);                 \
            fAl[buf][i] = *(const b8v*)(X + sb + HALF + oA[i]);          \
            fBh[buf][i] = *(const b8v*)(X + sb + oB[i]);                 \
            fBl[buf][i] = *(const b8v*)(X + sb + HALF + oB[i]);          \
        }                                                                \
    } while (0)

    LDG(0, 0);
#pragma unroll
    for (int kc = 0; kc < KCHUNK / 32; ++kc) {
        const int cb = kc & 1, nb = cb ^ 1;
        if (kc < KCHUNK / 32 - 1) LDG(nb, kc + 1);
#pragma unroll
        for (int i = 0; i < 4; ++i)
#pragma unroll
            for (int j = 0; j < 4; ++j) {
                acc[i][j] = __builtin_amdgcn_mfma_f32_16x16x32_bf16(fAh[cb][i], fBh[cb][j], acc[i][j], 0, 0, 0);
                acc[i][j] = __builtin_amdgcn_mfma_f32_16x16x32_bf16(fAh[cb][i], fBl[cb][j], acc[i][j], 0, 0, 0);
                acc[i][j] = __builtin_amdgcn_mfma_f32_16x16x32_bf16(fAl[cb][i], fBh[cb][j], acc[i][j], 0, 0, 0);
            }
    }
#undef LDG

    float* pt = part + (((size_t)pairIdx * BATCH + b) * KSPLIT + z) * 4096;
#pragma unroll
    for (int i = 0; i < 4; ++i)
#pragma unroll
        for (int j = 0; j < 4; ++j)
#pragma unroll
            for (int reg = 0; reg < 4; ++reg) {
                int row = i * 16 + q * 4 + reg;
                int col = j * 16 + r;
                pt[row * 64 + col] = acc[i][j][reg];
            }
}

// ---------------------------------------------------------------------------
// reduce partials -> a and z0 (interleaved fragment-major), mirrored via LDS
// ---------------------------------------------------------------------------
__global__ __launch_bounds__(256) void k_reduce(
    const float* __restrict__ part, const float* __restrict__ sbuf,
    const float* __restrict__ trbuf,
    unsigned short* __restrict__ A, unsigned short* __restrict__ Z) {
    const int b = blockIdx.y;
    int p = blockIdx.x, tm = 0, rem = 4;
    while (p >= rem) { p -= rem; ++tm; --rem; }
    const int tn = tm + p;

    const float* pb = part + ((size_t)blockIdx.x * BATCH + b) * KSPLIT * 4096;
    const int t = threadIdx.x;
    const int row = t >> 2, c0 = (t & 3) * 16;

    float s[16];
#pragma unroll
    for (int u = 0; u < 16; ++u) s[u] = 0.f;
    for (int sp = 0; sp < KSPLIT; ++sp) {
        const float* q4 = pb + sp * 4096 + row * 64 + c0;
#pragma unroll
        for (int u4 = 0; u4 < 4; ++u4) {
            float4 v = *(const float4*)(q4 + u4 * 4);
            s[u4 * 4 + 0] += v.x; s[u4 * 4 + 1] += v.y;
            s[u4 * 4 + 2] += v.z; s[u4 * 4 + 3] += v.w;
        }
    }

    const float invn = 1.f / (float)HW, invn2 = invn * invn;
    const float tr = trbuf[b];
    const int gi = tm * 64 + row;
    const float si = sbuf[b * C + gi];
    const size_t mb = (size_t)b * 8 * SLAB;

    __shared__ unsigned short tAh[64][66], tAl[64][66], tZh[64][66], tZl[64][66];
    unsigned short vAh[16], vAl[16], vZh[16], vZl[16];
#pragma unroll
    for (int u = 0; u < 16; ++u) {
        int gj = tn * 64 + c0 + u;
        float sj = sbuf[b * C + gj];
        float a = (s[u] * invn - si * sj * invn2) / tr;
        split2(a, vAh[u], vAl[u]);
        float zv = ((gi == gj) ? 1.5f : 0.f) - 0.5f * a;
        split2(zv, vZh[u], vZl[u]);
        tAh[row][c0 + u] = vAh[u]; tAl[row][c0 + u] = vAl[u];
        tZh[row][c0 + u] = vZh[u]; tZl[row][c0 + u] = vZl[u];
    }
#pragma unroll
    for (int u4 = 0; u4 < 4; ++u4) {
        const int col0 = tn * 64 + c0 + u4 * 4;
        const size_t off = mb + (size_t)(col0 >> 5) * SLAB + (size_t)gi * 32 + (col0 & 31);
        *(ushort4*)&A[off] = *(ushort4*)&vAh[u4 * 4];
        *(ushort4*)&A[off + HALF] = *(ushort4*)&vAl[u4 * 4];
        *(ushort4*)&Z[off] = *(ushort4*)&vZh[u4 * 4];
        *(ushort4*)&Z[off + HALF] = *(ushort4*)&vZl[u4 * 4];
    }
    if (tm != tn) {
        __syncthreads();
        const int mr = t >> 2, mc0 = (t & 3) * 16;
        const int gim = tn * 64 + mr;
        unsigned short wAh[16], wAl[16], wZh[16], wZl[16];
#pragma unroll
        for (int u = 0; u < 16; ++u) {
            wAh[u] = tAh[mc0 + u][mr]; wAl[u] = tAl[mc0 + u][mr];
            wZh[u] = tZh[mc0 + u][mr]; wZl[u] = tZl[mc0 + u][mr];
        }
#pragma unroll
        for (int u4 = 0; u4 < 4; ++u4) {
            const int col0 = tm * 64 + mc0 + u4 * 4;
            const size_t off = mb + (size_t)(col0 >> 5) * SLAB + (size_t)gim * 32 + (col0 & 31);
            *(ushort4*)&A[off] = *(ushort4*)&wAh[u4 * 4];
            *(ushort4*)&A[off + HALF] = *(ushort4*)&wAl[u4 * 4];
            *(ushort4*)&Z[off] = *(ushort4*)&wZh[u4 * 4];
            *(ushort4*)&Z[off + HALF] = *(ushort4*)&wZl[u4 * 4];
        }
    }
}

// ---------------------------------------------------------------------------
// NS core: one wave, 32x32 tile, K=256, interleaved fragment-major loads,
// register dbuf. 4x the blocks of the 64-tile version -> 2-4 waves/SIMD TLP.
// Accumulation order per output element identical to the 64-tile version.
// ---------------------------------------------------------------------------
__device__ __forceinline__ void wave_gemm32(
    const unsigned short* __restrict__ A, const unsigned short* __restrict__ B,
    int rowA, int rowB, f4v acc[2][2]) {
    const int lane = threadIdx.x & 63;
    const int q = lane >> 4, r = lane & 15;
    int oA[2], oB[2];
#pragma unroll
    for (int i = 0; i < 2; ++i) {
        oA[i] = (rowA + i * 16 + r) * 32 + q * 8;
        oB[i] = (rowB + i * 16 + r) * 32 + q * 8;
    }
    b8v fAh[2][2], fAl[2][2], fBh[2][2], fBl[2][2];
#define LD(buf, kc)                                              \
    do {                                                         \
        const size_t sb = (size_t)(kc) * SLAB;                   \
        for (int i = 0; i < 2; ++i) {                            \
            fAh[buf][i] = *(const b8v*)(A + sb + oA[i]);         \
            fAl[buf][i] = *(const b8v*)(A + sb + HALF + oA[i]);  \
            fBh[buf][i] = *(const b8v*)(B + sb + oB[i]);         \
            fBl[buf][i] = *(const b8v*)(B + sb + HALF + oB[i]);  \
        }                                                        \
    } while (0)

    LD(0, 0);
#pragma unroll
    for (int kc = 0; kc < 8; ++kc) {
        const int cb = kc & 1, nb = cb ^ 1;
        if (kc < 7) LD(nb, kc + 1);
#pragma unroll
        for (int i = 0; i < 2; ++i)
#pragma unroll
            for (int j = 0; j < 2; ++j) {
                acc[i][j] = __builtin_amdgcn_mfma_f32_16x16x32_bf16(fAh[cb][i], fBh[cb][j], acc[i][j], 0, 0, 0);
                acc[i][j] = __builtin_amdgcn_mfma_f32_16x16x32_bf16(fAh[cb][i], fBl[cb][j], acc[i][j], 0, 0, 0);
                acc[i][j] = __builtin_amdgcn_mfma_f32_16x16x32_bf16(fAl[cb][i], fBh[cb][j], acc[i][j], 0, 0, 0);
            }
    }
#undef LD
}

// store one 32x32 result tile into interleaved fragment-major D (direct)
__device__ __forceinline__ void store_tile32(
    unsigned short* __restrict__ D, int tm, int tn, const f4v acc[2][2], bool modeT) {
    const int lane = threadIdx.x & 63, q = lane >> 4, r = lane & 15;
#pragma unroll
    for (int i = 0; i < 2; ++i)
#pragma unroll
        for (int j = 0; j < 2; ++j) {
            const int gj = tn * 32 + j * 16 + r;
            const size_t cbase = (size_t)(gj >> 5) * SLAB + (gj & 31);
#pragma unroll
            for (int reg = 0; reg < 4; ++reg) {
                const int gi = tm * 32 + i * 16 + q * 4 + reg;
                float v = acc[i][j][reg];
                if (modeT) v = ((gi == gj) ? 1.5f : 0.f) - 0.5f * v;
                unsigned short h, l;
                split2(v, h, l);
                D[cbase + (size_t)gi * 32] = h;
                D[cbase + HALF + (size_t)gi * 32] = l;
            }
        }
}

// MODE 0: D = acc ; MODE 1: D = 1.5I - 0.5 acc ; MODE 2: triuvec(acc*sqrt(tr))
// XCD-pinned flat grid: batch b always lands on XCD b%8.
// MODE 0/1: grid 2048 (8 XCD x 4 b x 64 tiles). MODE 2: 1152 (8 x 4 x 36 tri).
template <int MODE>
__global__ __launch_bounds__(64, 1) void k_t64(
    const unsigned short* __restrict__ A, const unsigned short* __restrict__ B,
    unsigned short* __restrict__ D, float* __restrict__ outF,
    const float* __restrict__ strbuf) {
    const int bid = blockIdx.x;
    const int x8 = bid & 7;
    const int w = bid >> 3;
    int b, tm = 0, tn = 0;
    if (MODE == 2) {
        b = x8 + 8 * (w / 36);
        int p = w % 36, rem = 8;
        while (p >= rem) { p -= rem; ++tm; --rem; }
        tn = tm + p;
    } else {
        b = x8 + 8 * (w >> 6);
        const int tile = w & 63;
        tm = tile >> 3; tn = tile & 7;
    }
    const size_t mo = (size_t)b * 8 * SLAB;
    f4v acc[2][2] = {};
    wave_gemm32(A + mo, B + mo, tm * 32, tn * 32, acc);

    if (MODE == 2) {
        const int lane = threadIdx.x & 63, q = lane >> 4, r = lane & 15;
        const float sc = strbuf[b];
#pragma unroll
        for (int i = 0; i < 2; ++i)
#pragma unroll
            for (int j = 0; j < 2; ++j) {
                const int gj = tn * 32 + j * 16 + r;
#pragma unroll
                for (int reg = 0; reg < 4; ++reg) {
                    const int gi = tm * 32 + i * 16 + q * 4 + reg;
                    if (gj >= gi)
                        outF[(size_t)b * OUTROW + (size_t)(gi * C - (gi * (gi - 1)) / 2) +
                             (gj - gi)] = acc[i][j][reg] * sc;
                }
            }
    } else {
        store_tile32(D + mo, tm, tn, acc, MODE == 1);
    }
}

// fused Ynew = Y@T, Znew = T@Z ; XCD-pinned flat grid (4096 blocks)
__global__ __launch_bounds__(64, 1) void k_yz64(
    const unsigned short* __restrict__ Y, const unsigned short* __restrict__ T,
    const unsigned short* __restrict__ Z,
    unsigned short* __restrict__ Yn, unsigned short* __restrict__ Zn) {
    const int bid = blockIdx.x;
    const int x8 = bid & 7;
    const int w = bid >> 3;                 // 0..511
    const int zz = w >> 8;                  // 0: Y@T, 1: T@Z
    const int ww = w & 255;
    const int b = x8 + 8 * (ww >> 6);
    const int tile = ww & 63;
    const int tm = tile >> 3, tn = tile & 7;

    const unsigned short* Am = zz ? T : Y;
    const unsigned short* Bm = zz ? Z : T;
    unsigned short* Dm = zz ? Zn : Yn;

    const size_t mo = (size_t)b * 8 * SLAB;
    f4v acc[2][2] = {};
    wave_gemm32(Am + mo, Bm + mo, tm * 32, tn * 32, acc);
    store_tile32(Dm + mo, tm, tn, acc, false);
}

// ---------------------------------------------------------------------------
extern "C" void kernel_launch(void* const* d_in, const int* in_sizes, int n_in,
                              void* d_out, int out_size, void* d_ws, size_t ws_size,
                              hipStream_t stream) {
    const float* x = (const float*)d_in[0];
    float* out = (float*)d_out;

    unsigned short* W = (unsigned short*)d_ws;
    const size_t XS = (size_t)BATCH * KC32 * SLAB;   // interleaved X shorts
    const size_t MS = (size_t)BATCH * 8 * SLAB;      // one interleaved matrix set
    unsigned short* X = W;
    float* sbuf = (float*)(X + XS);
    float* trbuf = sbuf + BATCH * C;
    float* strbuf = trbuf + BATCH;
    unsigned short* P = (unsigned short*)(strbuf + BATCH);
    unsigned short* PA = P + 0 * MS;
    unsigned short* PB = P + 1 * MS;
    unsigned short* PC = P + 2 * MS;
    unsigned short* PD = P + 3 * MS;
    unsigned short* PE = P + 4 * MS;
    // fp32 gram partials alias PC.. (dead until Y0 is written)
    float* part = (float*)PC;                         // 10*32*7*4096 floats
    // prep sum partials alias PA (dead until k_reduce writes it)
    float* psum = (float*)PA;                         // 32*49*256 floats
    float* qsum = psum + (size_t)BATCH * KCG * 256;

    k_prep<<<dim3(BATCH * KCG), 256, 0, stream>>>(x, X, psum, qsum);
    k_tr<<<dim3(BATCH), 256, 0, stream>>>(psum, qsum, sbuf, trbuf, strbuf);
    k_gram_split<<<dim3(10 * BATCH * KSPLIT), 64, 0, stream>>>(X, part);
    k_reduce<<<dim3(10, BATCH), 256, 0, stream>>>(part, sbuf, trbuf, PA, PB);

    dim3 g2048(2048);
    // Y0 = a @ z0 -> PC
    k_t64<0><<<g2048, 64, 0, stream>>>(PA, PB, PC, nullptr, strbuf);
    // it0: T0 = 1.5I - 0.5 Z0@Y0 = PB@PC -> PD ; Y1 = PC@PD -> PA ; Z1 = PD@PB -> PE
    k_t64<1><<<g2048, 64, 0, stream>>>(PB, PC, PD, nullptr, strbuf);
    k_yz64<<<dim3(4096), 64, 0, stream>>>(PC, PD, PB, PA, PE);
    // it1: T1 = PE@PA -> PB ; Y2 = PA@PB -> PC ; Z2 = PB@PE -> PD
    k_t64<1><<<g2048, 64, 0, stream>>>(PE, PA, PB, nullptr, strbuf);
    k_yz64<<<dim3(4096), 64, 0, stream>>>(PA, PB, PE, PC, PD);
    // it2: T2 = PD@PC -> PA ; Y3 = PC@PA -> PB ; Z3 = PA@PD -> PE
    k_t64<1><<<g2048, 64, 0, stream>>>(PD, PC, PA, nullptr, strbuf);
    k_yz64<<<dim3(4096), 64, 0, stream>>>(PC, PA, PD, PB, PE);
    // it3: T3 = PE@PB -> PC ; out = triuvec((PB@PC) * sqrt(tr))
    k_t64<1><<<g2048, 64, 0, stream>>>(PE, PB, PC, nullptr, strbuf);
    k_t64<2><<<dim3(1152), 64, 0, stream>>>(PB, PC, nullptr, out, strbuf);
}